// Round 8
// baseline (1280.529 us; speedup 1.0000x reference)
//
#include <hip/hip_runtime.h>

typedef unsigned short u16;
typedef __attribute__((ext_vector_type(8))) short bf16x8;   // 8 bf16 in 4 VGPRs
typedef __attribute__((ext_vector_type(4))) float f32x4;
typedef __attribute__((ext_vector_type(4))) unsigned int u32x4;
typedef __attribute__((ext_vector_type(2))) unsigned int u32x2;

#define MROWS 18
#define MT 2
// element-index XOR swizzles (bank-conflict breakers):
#define SWZ(r,c)  ((c) ^ (((r)&7)<<3))        // bf16 rows of 256 (512B stride)
#define SWZV(n,j) ((j) ^ (((n)&3)<<3))        // s_vT rows of 32 u16 (64B stride)

__device__ inline u16 f2bf(float f){
  unsigned int u = __float_as_uint(f);
  return (u16)((u + 0x7fffu + ((u>>16)&1u)) >> 16);
}
__device__ inline unsigned int packbf(float a, float b){
  return (unsigned int)f2bf(a) | ((unsigned int)f2bf(b)<<16);
}
__device__ inline float bfloat_lo(unsigned int u){ return __uint_as_float(u<<16); }
__device__ inline float bfloat_hi(unsigned int u){ return __uint_as_float(u & 0xffff0000u); }
__device__ inline float bf2f(u16 h){ return __uint_as_float(((unsigned int)h)<<16); }
__device__ inline float wred(float v){
  #pragma unroll
  for (int m=1;m<64;m<<=1) v += __shfl_xor(v, m, 64);
  return v;
}
__device__ inline float silu_f(float x){ return x / (1.f + __expf(-x)); }
__device__ inline f32x4 mfma16(bf16x8 a, bf16x8 b, f32x4 c){
  return __builtin_amdgcn_mfma_f32_16x16x32_bf16(a, b, c, 0, 0, 0);
}

struct Params {
  const float *sigIn;
  const float *bn_g, *bn_b;
  const float *cWq,*cWk,*cWv,*cbq,*cbk,*cbv,*cbias_k,*cbias_v,*cWo,*cbo;
  const float *xbv, *xbias_v, *xbo;
  const float *b1,*b2,*b3;
  const float *g_cas,*b_cas,*g_ff,*b_ff,*g_fin,*b_fin;
  const u16 *Wv,*Wo,*Wq3,*W1b,*W2b,*W3p;
  const float *bias3, *ecr_t, *mu, *rstd;
  float *out;
};

// ---------------- prep: convert weights to bf16, build fused q-proj weights ----------------
__global__ void k_prep(const float* __restrict__ xWq, const float* __restrict__ xWk,
                       const float* __restrict__ xWv, const float* __restrict__ xWo,
                       const float* __restrict__ xbq, const float* __restrict__ xbk,
                       const float* __restrict__ xbias_k,
                       const float* __restrict__ W1, const float* __restrict__ W2,
                       const float* __restrict__ W3,
                       u16* Wv, u16* Wo, u16* Wq3, u16* W1b, u16* W2b, u16* W3p, float* bias3){
  const int gid = blockIdx.x*blockDim.x + threadIdx.x;
  const int gsz = gridDim.x*blockDim.x;
  for (int i=gid;i<65536;i+=gsz) Wv[i]=f2bf(xWv[i]);
  for (int i=gid;i<65536;i+=gsz) Wo[i]=f2bf(xWo[i]);
  for (int i=gid;i<8192;i+=gsz)  W1b[i]=f2bf(W1[i]);
  for (int i=gid;i<512;i+=gsz)   W2b[i]=f2bf(W2[i]);
  for (int i=gid;i<8192;i+=gsz){ int o=i>>5, k=i&31; W3p[i] = (k<16)? f2bf(W3[o*16+k]) : (u16)0; }
  for (int i=gid;i<8192;i+=gsz){           // Wq3[32][256]: rows 0-7 qw, 8-15 qb, 16-23 q2, 24-31 zero
    int r=i>>8, c=i&255;
    u16 outv = 0;
    if (r<24){
      int h=r&7, sel=r>>3;
      const float* vec = sel==0? xWk : (sel==1? xbk : xbias_k);
      float s=0.f;
      for (int d=0;d<32;++d) s += xWq[(size_t)(h*32+d)*256+c]*vec[h*32+d];
      outv = f2bf(s);
    }
    Wq3[i]=outv;
  }
  for (int i=gid;i<24;i+=gsz){
    int h=i&7, sel=i>>3;
    const float* vec = sel==0? xWk : (sel==1? xbk : xbias_k);
    float s=0.f; for (int d=0;d<32;++d) s += xbq[h*32+d]*vec[h*32+d];
    bias3[i]=s;
  }
}

// ---------------- ec_raw^T = (ctx @ Ws^T + bs)^T  -> ecr_t[j][b] ----------------
__global__ void k_ec(const float* __restrict__ ctx, const float* __restrict__ Ws,
                     const float* __restrict__ bs, float* __restrict__ ecr_t){
  const int wave = threadIdx.x>>6, lane = threadIdx.x&63;
  const int b = blockIdx.x*4 + wave;
  const float* c = ctx + (size_t)b*512 + lane*8;
  const float4 a0 = *(const float4*)c, a1 = *(const float4*)(c+4);
  float cv[8] = {a0.x,a0.y,a0.z,a0.w,a1.x,a1.y,a1.z,a1.w};
  #pragma unroll 1
  for (int j=0;j<18;++j){
    const float* w = Ws + j*512 + lane*8;
    const float4 w0 = *(const float4*)w, w1 = *(const float4*)(w+4);
    float s = cv[0]*w0.x + cv[1]*w0.y + cv[2]*w0.z + cv[3]*w0.w
            + cv[4]*w1.x + cv[5]*w1.y + cv[6]*w1.z + cv[7]*w1.w;
    s = wred(s);
    if (lane==0) ecr_t[(size_t)j*4096 + b] = s + bs[j];
  }
}

// ---------------- deterministic batch-norm stats, one block per feature j ----------------
__global__ void k_bn(const float* __restrict__ ecr_t, float* __restrict__ mu, float* __restrict__ rstd){
  __shared__ float red[256];
  const int j = blockIdx.x, tid = threadIdx.x;
  float s=0.f, s2=0.f;
  for (int b=tid;b<4096;b+=256){ float v = ecr_t[(size_t)j*4096+b]; s+=v; s2+=v*v; }
  red[tid]=s; __syncthreads();
  for (int o=128;o>0;o>>=1){ if(tid<o) red[tid]+=red[tid+o]; __syncthreads(); }
  float S = red[0]; __syncthreads();
  red[tid]=s2; __syncthreads();
  for (int o=128;o>0;o>>=1){ if(tid<o) red[tid]+=red[tid+o]; __syncthreads(); }
  float S2 = red[0];
  if (tid==0){ float m = S*(1.f/4096.f); float v = S2*(1.f/4096.f) - m*m;
               mu[j]=m; rstd[j]=rsqrtf(v+1e-5f); }
}

// ---------------- fused 4-layer decoder: 512 thr (8 waves), 1 batch/block ----------------
// (512,4): cap 128 unified regs -> 4 waves/SIMD -> 2 blocks x 8 waves = 16 waves/CU.
// r2-r4 lesson: the old fat-VALU P4 spilled at this cap; here every phase's live set is
// kept under ~90 regs (on-the-fly P fragments, no big per-lane arrays).
__global__ __launch_bounds__(512, 4) void k_main(Params P){
  __shared__ __attribute__((aligned(16))) u16 s_sig[MROWS][256];  // residual, bf16, SWZ
  __shared__ __attribute__((aligned(16))) u16 s_ns [MROWS][256];  // ns / ca, bf16, SWZ
  __shared__ __attribute__((aligned(16))) u16 s_vT [256][32];     // V^T (+xbias_v @k=18), SWZV
  __shared__ __attribute__((aligned(16))) u16 s_h1 [MROWS][32];   // FFN hidden
  __shared__ float s_qq[MROWS][28];                               // qw|qb|q2 (cols 0..23; pad 28 vs banks)
  __shared__ float s_ec[MROWS];
  __shared__ float s_mx [8][MROWS];                               // softmax row max
  __shared__ float s_inv[8][MROWS];                               // 1/den

  const int tid  = threadIdx.x;
  const int wave = tid >> 6;       // 0..7
  const int lane = tid & 63;
  const int lr   = lane & 15;
  const int lkg  = lane >> 4;
  const int kof  = lkg * 8;
  const int dr   = lkg * 4;
  const int b0   = blockIdx.x;
  const float scale = 0.17677669529663687f; // 1/sqrt(32)

  // ---- init
  for (int idx = tid*8; idx < MROWS*256; idx += 512*8){
    const int row = idx >> 8, col = idx & 255;
    const float* src = P.sigIn + (size_t)b0*18*256 + idx;
    const float4 a = *(const float4*)src;
    const float4 b = *(const float4*)(src+4);
    u32x4 w;
    w[0]=packbf(a.x,a.y); w[1]=packbf(a.z,a.w);
    w[2]=packbf(b.x,b.y); w[3]=packbf(b.z,b.w);
    *(u32x4*)&s_sig[row][SWZ(row,col)] = w;
  }
  if (tid < 256){
    const int n = tid;
    s_vT[n][SWZV(n,19)] = 0;
    #pragma unroll
    for (int jp=10; jp<16; ++jp) *(unsigned int*)&s_vT[n][SWZV(n,2*jp)] = 0u;
    s_vT[n][SWZV(n,18)] = f2bf(P.xbias_v[n]);
  }
  if (tid < MROWS){
    const float raw = P.ecr_t[(size_t)tid*4096 + b0];
    s_ec[tid] = (raw - P.mu[tid]) * P.rstd[tid] * P.bn_g[tid] + P.bn_b[tid];
  }
  __syncthreads();

  auto ln_rows = [&](const float* g, const float* bvec, int wbase, int wstep){
    for (int r = wbase; r < MROWS; r += wstep){
      const int col = lane*4;
      const u32x2 raw = *(const u32x2*)&s_sig[r][SWZ(r,col)];
      const float x0 = bfloat_lo(raw[0]), x1 = bfloat_hi(raw[0]);
      const float x2 = bfloat_lo(raw[1]), x3 = bfloat_hi(raw[1]);
      const float m = wred(x0+x1+x2+x3)*(1.f/256.f);
      const float d0=x0-m, d1=x1-m, d2=x2-m, d3=x3-m;
      const float rs = rsqrtf(wred(d0*d0+d1*d1+d2*d2+d3*d3)*(1.f/256.f)+1e-10f);
      const float4 gv = *(const float4*)(g+col);
      const float4 bv = *(const float4*)(bvec+col);
      u32x2 o;
      o[0] = packbf(d0*rs*gv.x+bv.x, d1*rs*gv.y+bv.y);
      o[1] = packbf(d2*rs*gv.z+bv.z, d3*rs*gv.w+bv.w);
      *(u32x2*)&s_ns[r][SWZ(r,col)] = o;
    }
  };

  for (int layer = 0; layer < 4; ++layer){
    // ---- P0 (wave 0): scalar ec self-attention || P1 (waves 1-7): LN(sig) w/ ln_cas
    if (wave == 0){
      if (lane < MROWS){
        const int i = lane;
        const float cwq=P.cWq[0], cbq=P.cbq[0], cwk=P.cWk[0], cbk=P.cbk[0];
        const float cwv=P.cWv[0], cbv=P.cbv[0], ck1=P.cbias_k[0], cv1=P.cbias_v[0];
        const float cwo=P.cWo[0], cbo=P.cbo[0];
        const float qi = s_ec[i]*cwq + cbq;
        float mx = qi*ck1;
        #pragma unroll
        for (int j=0;j<18;++j) mx = fmaxf(mx, qi*(s_ec[j]*cwk + cbk));
        float den=0.f, o=0.f;
        #pragma unroll
        for (int j=0;j<18;++j){
          const float pp=__expf(qi*(s_ec[j]*cwk + cbk)-mx);
          den+=pp; o+=pp*(s_ec[j]*cwv+cbv);
        }
        const float pp=__expf(qi*ck1-mx); den+=pp; o+=pp*cv1;
        s_ec[i] = s_ec[i] + (o/den)*cwo + cbo;   // lockstep: all reads precede write
      }
    } else {
      ln_rows(P.g_cas, P.b_cas, wave-1, 7);
    }
    __syncthreads();

    // ---- P2+P3: v = ns@Wv^T + xbv -> s_vT ; fused q-proj (ns@Wq3^T) -> s_qq
    // jobs: wave w -> Wv ntiles {w, 8+w}; waves 0,1 additionally Wq3 ntile w.
    {
      f32x4 acc[2][MT]; f32x4 accQ[MT];
      #pragma unroll
      for (int j=0;j<2;++j){ acc[j][0]=f32x4{0,0,0,0}; acc[j][1]=f32x4{0,0,0,0}; }
      accQ[0]=f32x4{0,0,0,0}; accQ[1]=f32x4{0,0,0,0};
      for (int kk=0; kk<8; ++kk){
        const int k0 = kk*32 + kof;
        bf16x8 afr[MT];
        #pragma unroll
        for (int mt=0;mt<MT;++mt){
          const int row = mt*16 + lr;
          u32x4 raw = u32x4{0u,0u,0u,0u};
          if (row < MROWS) raw = *(const u32x4*)&s_ns[row][SWZ(row,k0)];
          afr[mt] = __builtin_bit_cast(bf16x8, raw);
        }
        #pragma unroll
        for (int j=0;j<2;++j){
          const int n = (j*8+wave)*16 + lr;
          const bf16x8 bfr = __builtin_bit_cast(bf16x8, *(const u32x4*)(P.Wv + (size_t)n*256 + k0));
          #pragma unroll
          for (int mt=0;mt<MT;++mt) acc[j][mt] = mfma16(afr[mt], bfr, acc[j][mt]);
        }
        if (wave < 2){
          const bf16x8 bq = __builtin_bit_cast(bf16x8, *(const u32x4*)(P.Wq3 + (size_t)(wave*16+lr)*256 + k0));
          #pragma unroll
          for (int mt=0;mt<MT;++mt) accQ[mt] = mfma16(afr[mt], bq, accQ[mt]);
        }
      }
      #pragma unroll
      for (int j=0;j<2;++j){
        const int n = (j*8+wave)*16 + lr;
        const float bias = P.xbv[n];
        { // mt0: rows dr..dr+3 -> s_vT cols dr..dr+3 (4-aligned run, SWZV-safe)
          u32x2 w;
          w[0] = packbf(acc[j][0][0]+bias, acc[j][0][1]+bias);
          w[1] = packbf(acc[j][0][2]+bias, acc[j][0][3]+bias);
          *(u32x2*)&s_vT[n][SWZV(n,dr)] = w;
        }
        if (dr == 0){ // mt1: rows 16,17 only
          s_vT[n][SWZV(n,16)] = f2bf(acc[j][1][0]+bias);
          s_vT[n][SWZV(n,17)] = f2bf(acc[j][1][1]+bias);
        }
      }
      if (wave < 2){
        const int c = wave*16 + lr;
        if (c < 24){
          const float bias = P.bias3[c];
          #pragma unroll
          for (int mt=0;mt<MT;++mt){
            #pragma unroll
            for (int q=0;q<4;++q){
              const int row = mt*16 + dr + q;
              if (row < MROWS) s_qq[row][c] = accQ[mt][q] + bias;
            }
          }
        }
      }
    }
    __syncthreads();

    // ---- P4: attention, head h = wave. a) stats (lanes<18); b) on-the-fly P-fragments + MFMA.
    {
      const int h = wave;
      if (lane < MROWS){
        const int i = lane;
        const float qw = s_qq[i][h]*scale, qb = s_qq[i][8+h]*scale, s18 = s_qq[i][16+h]*scale;
        float mx = s18;
        #pragma unroll
        for (int j=0;j<18;++j) mx = fmaxf(mx, qw*s_ec[j] + qb);
        float den = __expf(s18-mx);
        #pragma unroll
        for (int j=0;j<18;++j) den += __expf(qw*s_ec[j] + qb - mx);
        s_mx[h][i]  = mx;
        s_inv[h][i] = 1.f/den;
      }
      // same wave consumes: compiler orders ds ops via lgkmcnt; no barrier needed.
      bf16x8 a0, a1;
      { // tile0 row = lr (<16, always valid)
        const float qw = s_qq[lr][h]*scale, qb = s_qq[lr][8+h]*scale, s18 = s_qq[lr][16+h]*scale;
        const float mx = s_mx[h][lr], inv = s_inv[h][lr];
        u16 pa[8];
        #pragma unroll
        for (int e=0;e<8;++e){
          const int k = kof + e;
          const float ecv = s_ec[k<18 ? k : 0];
          float pv = (k<18) ? __expf(qw*ecv+qb-mx) : ((k==18) ? __expf(s18-mx) : 0.f);
          pa[e] = f2bf(pv*inv);
        }
        u32x4 w; 
        w[0]=(unsigned)pa[0]|((unsigned)pa[1]<<16); w[1]=(unsigned)pa[2]|((unsigned)pa[3]<<16);
        w[2]=(unsigned)pa[4]|((unsigned)pa[5]<<16); w[3]=(unsigned)pa[6]|((unsigned)pa[7]<<16);
        a0 = __builtin_bit_cast(bf16x8, w);
      }
      { // tile1 row = 16+lr (valid only lr<2)
        u32x4 w = u32x4{0u,0u,0u,0u};
        if (lr < 2){
          const int rI = 16+lr;
          const float qw = s_qq[rI][h]*scale, qb = s_qq[rI][8+h]*scale, s18 = s_qq[rI][16+h]*scale;
          const float mx = s_mx[h][rI], inv = s_inv[h][rI];
          u16 pa[8];
          #pragma unroll
          for (int e=0;e<8;++e){
            const int k = kof + e;
            const float ecv = s_ec[k<18 ? k : 0];
            float pv = (k<18) ? __expf(qw*ecv+qb-mx) : ((k==18) ? __expf(s18-mx) : 0.f);
            pa[e] = f2bf(pv*inv);
          }
          w[0]=(unsigned)pa[0]|((unsigned)pa[1]<<16); w[1]=(unsigned)pa[2]|((unsigned)pa[3]<<16);
          w[2]=(unsigned)pa[4]|((unsigned)pa[5]<<16); w[3]=(unsigned)pa[6]|((unsigned)pa[7]<<16);
        }
        a1 = __builtin_bit_cast(bf16x8, w);
      }
      #pragma unroll
      for (int nt=0;nt<2;++nt){
        const int vn = h*32 + nt*16 + lr;
        const bf16x8 b = __builtin_bit_cast(bf16x8, *(const u32x4*)&s_vT[vn][SWZV(vn,kof)]);
        const f32x4 d0 = mfma16(a0, b, f32x4{0,0,0,0});
        const f32x4 d1 = mfma16(a1, b, f32x4{0,0,0,0});
        #pragma unroll
        for (int q=0;q<4;++q){
          const int row = dr + q;                      // <16, valid
          s_ns[row][SWZ(row, h*32 + nt*16 + lr)] = f2bf(d0[q]);
        }
        if (dr == 0){
          #pragma unroll
          for (int q=0;q<2;++q){
            const int row = 16 + q;
            s_ns[row][SWZ(row, h*32 + nt*16 + lr)] = f2bf(d1[q]);
          }
        }
      }
    }
    __syncthreads();

    // ---- P5: sig += ca @ Wo^T + xbo   (2 ntiles/wave)
    {
      f32x4 acc[2][MT];
      #pragma unroll
      for (int j=0;j<2;++j){ acc[j][0]=f32x4{0,0,0,0}; acc[j][1]=f32x4{0,0,0,0}; }
      for (int kk=0; kk<8; ++kk){
        const int k0 = kk*32 + kof;
        bf16x8 afr[MT];
        #pragma unroll
        for (int mt=0;mt<MT;++mt){
          const int row = mt*16 + lr;
          u32x4 raw = u32x4{0u,0u,0u,0u};
          if (row < MROWS) raw = *(const u32x4*)&s_ns[row][SWZ(row,k0)];
          afr[mt] = __builtin_bit_cast(bf16x8, raw);
        }
        #pragma unroll
        for (int nt=0;nt<2;++nt){
          const int n = (wave*2+nt)*16 + lr;
          const bf16x8 bfr = __builtin_bit_cast(bf16x8, *(const u32x4*)(P.Wo + (size_t)n*256 + k0));
          #pragma unroll
          for (int mt=0;mt<MT;++mt) acc[nt][mt] = mfma16(afr[mt], bfr, acc[nt][mt]);
        }
      }
      #pragma unroll
      for (int nt=0;nt<2;++nt){
        const int n = (wave*2+nt)*16 + lr;
        const float bias = P.xbo[n];
        #pragma unroll
        for (int mt=0;mt<MT;++mt){
          #pragma unroll
          for (int q=0;q<4;++q){
            const int row = mt*16 + dr + q;
            if (row < MROWS){
              const int si = SWZ(row,n);
              s_sig[row][si] = f2bf(bf2f(s_sig[row][si]) + acc[nt][mt][q] + bias);
            }
          }
        }
      }
    }
    __syncthreads();

    // ---- P6: nf = LN(sig) with ln_ff
    ln_rows(P.g_ff, P.b_ff, wave, 8);
    __syncthreads();

    // ---- P7+P8 (waves 0,1; wave w owns M-tile w): h1 = silu(nf@W1^T+b1); h2 = silu(h1@W2^T+b2)
    if (wave < 2){
      f32x4 acc[2];
      acc[0]=f32x4{0,0,0,0}; acc[1]=f32x4{0,0,0,0};
      for (int kk=0; kk<8; ++kk){
        const int k0 = kk*32 + kof;
        const int row = wave*16 + lr;
        u32x4 raw = u32x4{0u,0u,0u,0u};
        if (row < MROWS) raw = *(const u32x4*)&s_ns[row][SWZ(row,k0)];
        const bf16x8 afr = __builtin_bit_cast(bf16x8, raw);
        #pragma unroll
        for (int nt=0;nt<2;++nt){
          const bf16x8 bfr = __builtin_bit_cast(bf16x8, *(const u32x4*)(P.W1b + (size_t)(nt*16+lr)*256 + k0));
          acc[nt] = mfma16(afr, bfr, acc[nt]);
        }
      }
      #pragma unroll
      for (int nt=0;nt<2;++nt){
        const int c = nt*16 + lr;
        const float bias = P.b1[c];
        #pragma unroll
        for (int q=0;q<4;++q){
          const int row = wave*16 + dr + q;
          if (row < MROWS) s_h1[row][c] = f2bf(silu_f(acc[nt][q] + bias));
        }
      }
      { // P8, same wave's rows
        const int row_a = wave*16 + lr;
        u32x4 raw = u32x4{0u,0u,0u,0u};
        if (row_a < MROWS) raw = *(const u32x4*)&s_h1[row_a][kof];
        const bf16x8 a = __builtin_bit_cast(bf16x8, raw);
        const bf16x8 b = __builtin_bit_cast(bf16x8, *(const u32x4*)(P.W2b + (size_t)lr*32 + kof));
        f32x4 acc2 = mfma16(a, b, f32x4{0,0,0,0});
        const float bias = P.b2[lr];
        #pragma unroll
        for (int q=0;q<4;++q){
          const int row = wave*16 + dr + q;
          if (row < MROWS){
            s_h1[row][lr]    = f2bf(silu_f(acc2[q] + bias));
            s_h1[row][lr+16] = 0;
          }
        }
      }
    }
    __syncthreads();

    // ---- P9: sig += silu(h2 @ W3p^T + b3)  (2 ntiles/wave, K=32 padded)
    {
      bf16x8 afr[MT];
      #pragma unroll
      for (int mt=0;mt<MT;++mt){
        const int row = mt*16 + lr;
        u32x4 raw = u32x4{0u,0u,0u,0u};
        if (row < MROWS) raw = *(const u32x4*)&s_h1[row][kof];
        afr[mt] = __builtin_bit_cast(bf16x8, raw);
      }
      #pragma unroll
      for (int nt=0;nt<2;++nt){
        const int n = (wave*2+nt)*16 + lr;
        const bf16x8 bfr = __builtin_bit_cast(bf16x8, *(const u32x4*)(P.W3p + (size_t)n*32 + kof));
        const float b3v = P.b3[n];
        #pragma unroll
        for (int mt=0;mt<MT;++mt){
          const f32x4 acc = mfma16(afr[mt], bfr, f32x4{0,0,0,0});
          #pragma unroll
          for (int q=0;q<4;++q){
            const int row = mt*16 + dr + q;
            if (row < MROWS){
              const int si = SWZ(row,n);
              s_sig[row][si] = f2bf(bf2f(s_sig[row][si]) + silu_f(acc[q] + b3v));
            }
          }
        }
      }
    }
    __syncthreads();
  } // layers

  // ---- final LN -> out (f32)
  {
    for (int r = wave; r < MROWS; r += 8){
      const int col = lane*4;
      const u32x2 raw = *(const u32x2*)&s_sig[r][SWZ(r,col)];
      const float x0 = bfloat_lo(raw[0]), x1 = bfloat_hi(raw[0]);
      const float x2 = bfloat_lo(raw[1]), x3 = bfloat_hi(raw[1]);
      const float m = wred(x0+x1+x2+x3)*(1.f/256.f);
      const float d0=x0-m, d1=x1-m, d2=x2-m, d3=x3-m;
      const float rs = rsqrtf(wred(d0*d0+d1*d1+d2*d2+d3*d3)*(1.f/256.f)+1e-10f);
      const float4 gv = *(const float4*)(P.g_fin+col);
      const float4 bv = *(const float4*)(P.b_fin+col);
      float4 o;
      o.x = d0*rs*gv.x+bv.x; o.y = d1*rs*gv.y+bv.y;
      o.z = d2*rs*gv.z+bv.z; o.w = d3*rs*gv.w+bv.w;
      *(float4*)(P.out + ((size_t)b0*18 + r)*256 + col) = o;
    }
  }
}

extern "C" void kernel_launch(void* const* d_in, const int* in_sizes, int n_in,
                              void* d_out, int out_size, void* d_ws, size_t ws_size,
                              hipStream_t stream) {
  (void)in_sizes; (void)n_in; (void)out_size; (void)ws_size;
  const float* sigIn   = (const float*)d_in[0];
  const float* ctx     = (const float*)d_in[1];
  const float* Ws      = (const float*)d_in[2];
  const float* bs      = (const float*)d_in[3];
  const float* bn_g    = (const float*)d_in[4];
  const float* bn_b    = (const float*)d_in[5];
  const float* cWq     = (const float*)d_in[6];
  const float* cWk     = (const float*)d_in[7];
  const float* cWv     = (const float*)d_in[8];
  const float* cbq     = (const float*)d_in[9];
  const float* cbk     = (const float*)d_in[10];
  const float* cbv     = (const float*)d_in[11];
  const float* cbias_k = (const float*)d_in[12];
  const float* cbias_v = (const float*)d_in[13];
  const float* cWo     = (const float*)d_in[14];
  const float* cbo     = (const float*)d_in[15];
  const float* xWq     = (const float*)d_in[16];
  const float* xWk     = (const float*)d_in[17];
  const float* xWv     = (const float*)d_in[18];
  const float* xbq     = (const float*)d_in[19];
  const float* xbk     = (const float*)d_in[20];
  const float* xbv     = (const float*)d_in[21];
  const float* xbias_k = (const float*)d_in[22];
  const float* xbias_v = (const float*)d_in[23];
  const float* xWo     = (const float*)d_in[24];
  const float* xbo     = (const float*)d_in[25];
  const float* W1      = (const float*)d_in[26];
  const float* b1      = (const float*)d_in[27];
  const float* W2      = (const float*)d_in[28];
  const float* b2      = (const float*)d_in[29];
  const float* W3      = (const float*)d_in[30];
  const float* b3      = (const float*)d_in[31];
  const float* g_ff    = (const float*)d_in[32];
  const float* b_ff    = (const float*)d_in[33];
  const float* g_cas   = (const float*)d_in[34];
  const float* b_cas   = (const float*)d_in[35];
  const float* g_fin   = (const float*)d_in[36];
  const float* b_fin   = (const float*)d_in[37];

  char* ws = (char*)d_ws;
  u16*  Wv    = (u16*)(ws);             // 131072 B
  u16*  Wo    = (u16*)(ws + 131072);    // 131072 B
  u16*  Wq3   = (u16*)(ws + 262144);    // 16384 B
  u16*  W1b   = (u16*)(ws + 278528);    // 16384 B
  u16*  W2b   = (u16*)(ws + 294912);    // 1024 B
  u16*  W3p   = (u16*)(ws + 295936);    // 16384 B
  float* bias3= (float*)(ws + 312320);  // 96 B (pad to 128)
  float* ecr_t= (float*)(ws + 312448);  // 294912 B (transposed [18][4096])
  float* mu   = (float*)(ws + 607360);  // 72 B (pad)
  float* rstd = (float*)(ws + 607488);  // 72 B

  k_prep<<<dim3(64), dim3(256), 0, stream>>>(xWq, xWk, xWv, xWo, xbq, xbk, xbias_k,
                                             W1, W2, W3, Wv, Wo, Wq3, W1b, W2b, W3p, bias3);
  k_ec<<<dim3(1024), dim3(256), 0, stream>>>(ctx, Ws, bs, ecr_t);
  k_bn<<<dim3(18), dim3(256), 0, stream>>>(ecr_t, mu, rstd);

  Params P;
  P.sigIn = sigIn; P.bn_g = bn_g; P.bn_b = bn_b;
  P.cWq=cWq; P.cWk=cWk; P.cWv=cWv; P.cbq=cbq; P.cbk=cbk; P.cbv=cbv;
  P.cbias_k=cbias_k; P.cbias_v=cbias_v; P.cWo=cWo; P.cbo=cbo;
  P.xbv=xbv; P.xbias_v=xbias_v; P.xbo=xbo;
  P.b1=b1; P.b2=b2; P.b3=b3;
  P.g_cas=g_cas; P.b_cas=b_cas; P.g_ff=g_ff; P.b_ff=b_ff; P.g_fin=g_fin; P.b_fin=b_fin;
  P.Wv=Wv; P.Wo=Wo; P.Wq3=Wq3; P.W1b=W1b; P.W2b=W2b; P.W3p=W3p;
  P.bias3=bias3; P.ecr_t=ecr_t; P.mu=mu; P.rstd=rstd;
  P.out = (float*)d_out;

  k_main<<<dim3(4096), dim3(512), 0, stream>>>(P);
}

// Round 9
// 1011.997 us; speedup vs baseline: 1.2653x; 1.2653x over previous
//
#include <hip/hip_runtime.h>

typedef unsigned short u16;
typedef __attribute__((ext_vector_type(8))) short bf16x8;   // 8 bf16 in 4 VGPRs
typedef __attribute__((ext_vector_type(4))) float f32x4;
typedef __attribute__((ext_vector_type(4))) unsigned int u32x4;
typedef __attribute__((ext_vector_type(2))) unsigned int u32x2;

#define MROWS 36      // 2 batches * 18 rows
#define MT 3          // M-tiles of 16
// element-index XOR swizzles (bank-conflict breakers):
#define SWZ(r,c)  ((c) ^ (((r)&7)<<3))        // bf16 rows of 256 (512B stride)
#define SWZV(n,j) ((j) ^ (((n)&3)<<3))        // s_vT rows of 32 u16 (64B stride)

__device__ inline u16 f2bf(float f){
  unsigned int u = __float_as_uint(f);
  return (u16)((u + 0x7fffu + ((u>>16)&1u)) >> 16);
}
__device__ inline unsigned int packbf(float a, float b){
  return (unsigned int)f2bf(a) | ((unsigned int)f2bf(b)<<16);
}
__device__ inline float bfloat_lo(unsigned int u){ return __uint_as_float(u<<16); }
__device__ inline float bfloat_hi(unsigned int u){ return __uint_as_float(u & 0xffff0000u); }
__device__ inline float bf2f(u16 h){ return __uint_as_float(((unsigned int)h)<<16); }
__device__ inline float wred(float v){
  #pragma unroll
  for (int m=1;m<64;m<<=1) v += __shfl_xor(v, m, 64);
  return v;
}
__device__ inline float silu_f(float x){ return x / (1.f + __expf(-x)); }
__device__ inline f32x4 mfma16(bf16x8 a, bf16x8 b, f32x4 c){
  return __builtin_amdgcn_mfma_f32_16x16x32_bf16(a, b, c, 0, 0, 0);
}

struct Params {
  const float *sigIn;
  const float *bn_g, *bn_b;
  const float *cWq,*cWk,*cWv,*cbq,*cbk,*cbv,*cbias_k,*cbias_v,*cWo,*cbo;
  const float *xbv, *xbias_v, *xbo;
  const float *b1,*b2,*b3;
  const float *g_cas,*b_cas,*g_ff,*b_ff,*g_fin,*b_fin;
  const u16 *Wv,*Wo,*Wq3,*W1b,*W2b,*W3p;
  const float *bias3, *ecr_t, *mu, *rstd;
  float *out;
};

// ---------------- prep: convert weights to bf16, build fused q-proj weights ----------------
__global__ void k_prep(const float* __restrict__ xWq, const float* __restrict__ xWk,
                       const float* __restrict__ xWv, const float* __restrict__ xWo,
                       const float* __restrict__ xbq, const float* __restrict__ xbk,
                       const float* __restrict__ xbias_k,
                       const float* __restrict__ W1, const float* __restrict__ W2,
                       const float* __restrict__ W3,
                       u16* Wv, u16* Wo, u16* Wq3, u16* W1b, u16* W2b, u16* W3p, float* bias3){
  const int gid = blockIdx.x*blockDim.x + threadIdx.x;
  const int gsz = gridDim.x*blockDim.x;
  for (int i=gid;i<65536;i+=gsz) Wv[i]=f2bf(xWv[i]);
  for (int i=gid;i<65536;i+=gsz) Wo[i]=f2bf(xWo[i]);
  for (int i=gid;i<8192;i+=gsz)  W1b[i]=f2bf(W1[i]);
  for (int i=gid;i<512;i+=gsz)   W2b[i]=f2bf(W2[i]);
  for (int i=gid;i<8192;i+=gsz){ int o=i>>5, k=i&31; W3p[i] = (k<16)? f2bf(W3[o*16+k]) : (u16)0; }
  for (int i=gid;i<8192;i+=gsz){           // Wq3[32][256]: rows 0-7 qw, 8-15 qb, 16-23 q2, 24-31 zero
    int r=i>>8, c=i&255;
    u16 outv = 0;
    if (r<24){
      int h=r&7, sel=r>>3;
      const float* vec = sel==0? xWk : (sel==1? xbk : xbias_k);
      float s=0.f;
      for (int d=0;d<32;++d) s += xWq[(size_t)(h*32+d)*256+c]*vec[h*32+d];
      outv = f2bf(s);
    }
    Wq3[i]=outv;
  }
  for (int i=gid;i<24;i+=gsz){
    int h=i&7, sel=i>>3;
    const float* vec = sel==0? xWk : (sel==1? xbk : xbias_k);
    float s=0.f; for (int d=0;d<32;++d) s += xbq[h*32+d]*vec[h*32+d];
    bias3[i]=s;
  }
}

// ---------------- ec_raw^T = (ctx @ Ws^T + bs)^T  -> ecr_t[j][b] ----------------
__global__ void k_ec(const float* __restrict__ ctx, const float* __restrict__ Ws,
                     const float* __restrict__ bs, float* __restrict__ ecr_t){
  const int wave = threadIdx.x>>6, lane = threadIdx.x&63;
  const int b = blockIdx.x*4 + wave;
  const float* c = ctx + (size_t)b*512 + lane*8;
  const float4 a0 = *(const float4*)c, a1 = *(const float4*)(c+4);
  float cv[8] = {a0.x,a0.y,a0.z,a0.w,a1.x,a1.y,a1.z,a1.w};
  #pragma unroll 1
  for (int j=0;j<18;++j){
    const float* w = Ws + j*512 + lane*8;
    const float4 w0 = *(const float4*)w, w1 = *(const float4*)(w+4);
    float s = cv[0]*w0.x + cv[1]*w0.y + cv[2]*w0.z + cv[3]*w0.w
            + cv[4]*w1.x + cv[5]*w1.y + cv[6]*w1.z + cv[7]*w1.w;
    s = wred(s);
    if (lane==0) ecr_t[(size_t)j*4096 + b] = s + bs[j];
  }
}

// ---------------- deterministic batch-norm stats, one block per feature j ----------------
__global__ void k_bn(const float* __restrict__ ecr_t, float* __restrict__ mu, float* __restrict__ rstd){
  __shared__ float red[256];
  const int j = blockIdx.x, tid = threadIdx.x;
  float s=0.f, s2=0.f;
  for (int b=tid;b<4096;b+=256){ float v = ecr_t[(size_t)j*4096+b]; s+=v; s2+=v*v; }
  red[tid]=s; __syncthreads();
  for (int o=128;o>0;o>>=1){ if(tid<o) red[tid]+=red[tid+o]; __syncthreads(); }
  float S = red[0]; __syncthreads();
  red[tid]=s2; __syncthreads();
  for (int o=128;o>0;o>>=1){ if(tid<o) red[tid]+=red[tid+o]; __syncthreads(); }
  float S2 = red[0];
  if (tid==0){ float m = S*(1.f/4096.f); float v = S2*(1.f/4096.f) - m*m;
               mu[j]=m; rstd[j]=rsqrtf(v+1e-5f); }
}

// ---------------- fused 4-layer decoder: 256 thr, 2 batches/block, 2 blocks/CU ----------------
// (256,2) is the ONLY proven spill-free operating point (r1/r6/r7: 128 VGPR + AGPR, no scratch).
// r2-r4 and r8: any tighter cap (3-4 blocks or 128-total) -> 0.3-1.1 GB scratch HBM traffic.
// Perf comes from work-per-block amortization (M=36) + MFMA attention + fewer barriers.
__global__ __launch_bounds__(256, 2) void k_main(Params P){
  __shared__ __attribute__((aligned(16))) u16 s_sig[MROWS][256];   // residual, bf16, SWZ     18.0K
  __shared__ __attribute__((aligned(16))) u16 s_ns [MROWS][256];   // ns / ca, bf16, SWZ      18.0K
  __shared__ __attribute__((aligned(16))) u16 s_vT [2][256][32];   // per-batch V^T, SWZV     32.0K
  __shared__ __attribute__((aligned(16))) u16 s_h1 [MROWS][32];    // FFN hidden               2.25K
  __shared__ float s_qq[MROWS][28];                                // qw|qb|q2 planes          4.0K
  __shared__ float s_ec[MROWS];                                    // batch-norm'd ec (global rows)
  __shared__ float s_mx [8][MROWS];                                // softmax row max
  __shared__ float s_inv[8][MROWS];                                // 1/den

  const int tid  = threadIdx.x;
  const int wave = tid >> 6;
  const int lane = tid & 63;
  const int lr   = lane & 15;
  const int lkg  = lane >> 4;
  const int kof  = lkg * 8;
  const int dr   = lkg * 4;
  const int b0   = blockIdx.x;       // batch pair
  const float scale = 0.17677669529663687f; // 1/sqrt(32)

  // ---- init
  for (int idx = tid*8; idx < MROWS*256; idx += 256*8){
    const int row = idx >> 8, col = idx & 255;
    const float* src = P.sigIn + (size_t)b0*MROWS*256 + idx;
    const float4 a = *(const float4*)src;
    const float4 b = *(const float4*)(src+4);
    u32x4 w;
    w[0]=packbf(a.x,a.y); w[1]=packbf(a.z,a.w);
    w[2]=packbf(b.x,b.y); w[3]=packbf(b.z,b.w);
    *(u32x4*)&s_sig[row][SWZ(row,col)] = w;
  }
  {
    // s_vT cols 18..31 persist across layers: col 18 = xbias_v (the k=18 "bias key" row),
    // cols 19..31 = 0 (K-pad; stale 0xAA bits could be NaN and NaN*0=NaN in MFMA).
    const int n = tid;
    #pragma unroll
    for (int nb=0; nb<2; ++nb){
      s_vT[nb][n][SWZV(n,19)] = 0;
      #pragma unroll
      for (int jp=10; jp<16; ++jp) *(unsigned int*)&s_vT[nb][n][SWZV(n,2*jp)] = 0u;
      s_vT[nb][n][SWZV(n,18)] = f2bf(P.xbias_v[n]);
    }
  }
  if (tid < MROWS){
    const int nb = tid/18, j = tid - nb*18;
    const float raw = P.ecr_t[(size_t)j*4096 + (size_t)b0*2 + nb];
    s_ec[tid] = (raw - P.mu[j]) * P.rstd[j] * P.bn_g[j] + P.bn_b[j];
  }
  __syncthreads();

  auto ln_rows = [&](const float* g, const float* bvec, int wbase, int wstep){
    for (int r = wbase; r < MROWS; r += wstep){
      const int col = lane*4;
      const u32x2 raw = *(const u32x2*)&s_sig[r][SWZ(r,col)];
      const float x0 = bfloat_lo(raw[0]), x1 = bfloat_hi(raw[0]);
      const float x2 = bfloat_lo(raw[1]), x3 = bfloat_hi(raw[1]);
      const float m = wred(x0+x1+x2+x3)*(1.f/256.f);
      const float d0=x0-m, d1=x1-m, d2=x2-m, d3=x3-m;
      const float rs = rsqrtf(wred(d0*d0+d1*d1+d2*d2+d3*d3)*(1.f/256.f)+1e-10f);
      const float4 gv = *(const float4*)(g+col);
      const float4 bv = *(const float4*)(bvec+col);
      u32x2 o;
      o[0] = packbf(d0*rs*gv.x+bv.x, d1*rs*gv.y+bv.y);
      o[1] = packbf(d2*rs*gv.z+bv.z, d3*rs*gv.w+bv.w);
      *(u32x2*)&s_ns[r][SWZ(r,col)] = o;
    }
  };

  for (int layer = 0; layer < 4; ++layer){
    // ---- P0 (wave 0, lanes<36): scalar ec self-attn (both batches; wave-lockstep safe)
    //      || P1 (waves 1-3): ns = LN(sig) with ln_cas, 12 rows each
    if (wave == 0){
      if (lane < MROWS){
        const int nb = lane/18;
        const float cwq=P.cWq[0], cbq=P.cbq[0], cwk=P.cWk[0], cbk=P.cbk[0];
        const float cwv=P.cWv[0], cbv=P.cbv[0], ck1=P.cbias_k[0], cv1=P.cbias_v[0];
        const float cwo=P.cWo[0], cbo=P.cbo[0];
        const float qi = s_ec[lane]*cwq + cbq;
        float mx = qi*ck1;
        #pragma unroll
        for (int j=0;j<18;++j) mx = fmaxf(mx, qi*(s_ec[nb*18+j]*cwk + cbk));
        float den=0.f, o=0.f;
        #pragma unroll
        for (int j=0;j<18;++j){
          const float pp=__expf(qi*(s_ec[nb*18+j]*cwk + cbk)-mx);
          den+=pp; o+=pp*(s_ec[nb*18+j]*cwv+cbv);
        }
        const float pp=__expf(qi*ck1-mx); den+=pp; o+=pp*cv1;
        s_ec[lane] = s_ec[lane] + (o/den)*cwo + cbo;  // lockstep: all reads precede write
      }
    } else {
      ln_rows(P.g_cas, P.b_cas, wave-1, 3);
    }
    __syncthreads();

    // ---- P2+P3: v = ns@Wv^T + xbv -> s_vT[batch] (transposed); q-proj (ns@Wq3^T) -> s_qq
    {
      f32x4 accV[MT][4]; f32x4 accQ[MT];
      #pragma unroll
      for (int mt=0;mt<MT;++mt){
        accQ[mt] = f32x4{0,0,0,0};
        #pragma unroll
        for (int nt=0;nt<4;++nt) accV[mt][nt] = f32x4{0,0,0,0};
      }
      for (int kk=0; kk<8; ++kk){
        const int k0 = kk*32 + kof;
        bf16x8 afr[MT];
        #pragma unroll
        for (int mt=0;mt<MT;++mt){
          const int row = mt*16 + lr;
          u32x4 raw = u32x4{0u,0u,0u,0u};
          if (row < MROWS) raw = *(const u32x4*)&s_ns[row][SWZ(row,k0)];
          afr[mt] = __builtin_bit_cast(bf16x8, raw);
        }
        #pragma unroll
        for (int nt=0;nt<4;++nt){
          const int n = (wave*4+nt)*16 + lr;
          const bf16x8 bfr = __builtin_bit_cast(bf16x8, *(const u32x4*)(P.Wv + (size_t)n*256 + k0));
          #pragma unroll
          for (int mt=0;mt<MT;++mt) accV[mt][nt] = mfma16(afr[mt], bfr, accV[mt][nt]);
        }
        if (wave < 2){
          const bf16x8 bq = __builtin_bit_cast(bf16x8, *(const u32x4*)(P.Wq3 + (size_t)(wave*16+lr)*256 + k0));
          #pragma unroll
          for (int mt=0;mt<MT;++mt) accQ[mt] = mfma16(afr[mt], bq, accQ[mt]);
        }
      }
      #pragma unroll
      for (int nt=0;nt<4;++nt){
        const int n = (wave*4+nt)*16 + lr;
        const float bias = P.xbv[n];
        #pragma unroll
        for (int mt=0;mt<MT;++mt){
          #pragma unroll
          for (int q=0;q<4;++q){
            const int row = mt*16 + dr + q;
            if (row < MROWS){
              const int nb = row >= 18;
              const int lc = row - nb*18;
              s_vT[nb][n][SWZV(n,lc)] = f2bf(accV[mt][nt][q] + bias);
            }
          }
        }
      }
      if (wave < 2){
        const int c = wave*16 + lr;
        if (c < 24){
          const float bias = P.bias3[c];
          #pragma unroll
          for (int mt=0;mt<MT;++mt){
            #pragma unroll
            for (int q=0;q<4;++q){
              const int row = mt*16 + dr + q;
              if (row < MROWS) s_qq[row][c] = accQ[mt][q] + bias;
            }
          }
        }
      }
    }
    __syncthreads();

    // ---- P4: attention. Wave w owns heads {2w, 2w+1}; fully wave-local -> no internal barrier.
    // P4a: stats. lanes<36 each handle (nb,i) = its global row, for both owned heads.
    {
      if (lane < MROWS){
        const int nb = lane/18;
        #pragma unroll
        for (int hh=0; hh<2; ++hh){
          const int h = wave*2 + hh;
          const float qw = s_qq[lane][h]*scale, qb = s_qq[lane][8+h]*scale, s18 = s_qq[lane][16+h]*scale;
          float mx = s18;
          #pragma unroll
          for (int j=0;j<18;++j) mx = fmaxf(mx, qw*s_ec[nb*18+j] + qb);
          float den = __expf(s18-mx);
          #pragma unroll
          for (int j=0;j<18;++j) den += __expf(qw*s_ec[nb*18+j] + qb - mx);
          s_mx[h][lane]  = mx;
          s_inv[h][lane] = 1.f/den;
        }
      }
      // P4b: on-the-fly normalized P fragments + MFMA (same wave consumes its own stats;
      // compiler inserts lgkmcnt ordering for same-wave ds ops).
      #pragma unroll
      for (int hh=0; hh<2; ++hh){
        const int h = wave*2 + hh;
        #pragma unroll
        for (int nb=0; nb<2; ++nb){
          const int base = nb*18;
          bf16x8 a0, a1;
          { // tile0: local rows lr (<16)
            const int grow = base + lr;
            const float qw = s_qq[grow][h]*scale, qb = s_qq[grow][8+h]*scale, s18 = s_qq[grow][16+h]*scale;
            const float mx = s_mx[h][grow], inv = s_inv[h][grow];
            u16 pa[8];
            #pragma unroll
            for (int e=0;e<8;++e){
              const int k = kof + e;
              const float ecv = s_ec[base + (k<18 ? k : 0)];
              float pv = (k<18) ? __expf(qw*ecv+qb-mx) : ((k==18) ? __expf(s18-mx) : 0.f);
              pa[e] = f2bf(pv*inv);
            }
            u32x4 w;
            w[0]=(unsigned)pa[0]|((unsigned)pa[1]<<16); w[1]=(unsigned)pa[2]|((unsigned)pa[3]<<16);
            w[2]=(unsigned)pa[4]|((unsigned)pa[5]<<16); w[3]=(unsigned)pa[6]|((unsigned)pa[7]<<16);
            a0 = __builtin_bit_cast(bf16x8, w);
          }
          { // tile1: local rows 16,17 (lr<2)
            u32x4 w = u32x4{0u,0u,0u,0u};
            if (lr < 2){
              const int grow = base + 16 + lr;
              const float qw = s_qq[grow][h]*scale, qb = s_qq[grow][8+h]*scale, s18 = s_qq[grow][16+h]*scale;
              const float mx = s_mx[h][grow], inv = s_inv[h][grow];
              u16 pa[8];
              #pragma unroll
              for (int e=0;e<8;++e){
                const int k = kof + e;
                const float ecv = s_ec[base + (k<18 ? k : 0)];
                float pv = (k<18) ? __expf(qw*ecv+qb-mx) : ((k==18) ? __expf(s18-mx) : 0.f);
                pa[e] = f2bf(pv*inv);
              }
              w[0]=(unsigned)pa[0]|((unsigned)pa[1]<<16); w[1]=(unsigned)pa[2]|((unsigned)pa[3]<<16);
              w[2]=(unsigned)pa[4]|((unsigned)pa[5]<<16); w[3]=(unsigned)pa[6]|((unsigned)pa[7]<<16);
            }
            a1 = __builtin_bit_cast(bf16x8, w);
          }
          #pragma unroll
          for (int nt=0;nt<2;++nt){
            const int vn = h*32 + nt*16 + lr;
            const bf16x8 b = __builtin_bit_cast(bf16x8, *(const u32x4*)&s_vT[nb][vn][SWZV(vn,kof)]);
            const f32x4 d0 = mfma16(a0, b, f32x4{0,0,0,0});
            const f32x4 d1 = mfma16(a1, b, f32x4{0,0,0,0});
            #pragma unroll
            for (int q=0;q<4;++q){
              const int row = base + dr + q;
              s_ns[row][SWZ(row, h*32 + nt*16 + lr)] = f2bf(d0[q]);
            }
            if (dr == 0){
              #pragma unroll
              for (int q=0;q<2;++q){
                const int row = base + 16 + q;
                s_ns[row][SWZ(row, h*32 + nt*16 + lr)] = f2bf(d1[q]);
              }
            }
          }
        }
      }
    }
    __syncthreads();

    // ---- P5: sig += ca @ Wo^T + xbo
    {
      f32x4 acc[MT][4];
      #pragma unroll
      for (int mt=0;mt<MT;++mt){
        #pragma unroll
        for (int nt=0;nt<4;++nt) acc[mt][nt] = f32x4{0,0,0,0};
      }
      for (int kk=0; kk<8; ++kk){
        const int k0 = kk*32 + kof;
        bf16x8 afr[MT];
        #pragma unroll
        for (int mt=0;mt<MT;++mt){
          const int row = mt*16 + lr;
          u32x4 raw = u32x4{0u,0u,0u,0u};
          if (row < MROWS) raw = *(const u32x4*)&s_ns[row][SWZ(row,k0)];
          afr[mt] = __builtin_bit_cast(bf16x8, raw);
        }
        #pragma unroll
        for (int nt=0;nt<4;++nt){
          const int n = (wave*4+nt)*16 + lr;
          const bf16x8 bfr = __builtin_bit_cast(bf16x8, *(const u32x4*)(P.Wo + (size_t)n*256 + k0));
          #pragma unroll
          for (int mt=0;mt<MT;++mt) acc[mt][nt] = mfma16(afr[mt], bfr, acc[mt][nt]);
        }
      }
      #pragma unroll
      for (int nt=0;nt<4;++nt){
        const int n = (wave*4+nt)*16 + lr;
        const float bias = P.xbo[n];
        #pragma unroll
        for (int mt=0;mt<MT;++mt){
          #pragma unroll
          for (int q=0;q<4;++q){
            const int row = mt*16 + dr + q;
            if (row < MROWS){
              const int si = SWZ(row,n);
              s_sig[row][si] = f2bf(bf2f(s_sig[row][si]) + acc[mt][nt][q] + bias);
            }
          }
        }
      }
    }
    __syncthreads();

    // ---- P6: nf = LN(sig) with ln_ff (all 4 waves, 9 rows each)
    ln_rows(P.g_ff, P.b_ff, wave, 4);
    __syncthreads();

    // ---- P7+P8: wave w (<3) owns M-tile w. P7: h1 = silu(nf@W1^T+b1) for its rows;
    //      P8 (same wave, same rows, no barrier): h2 = silu(h1@W2^T+b2), K-pad cols zeroed.
    if (wave < MT){
      f32x4 acc[2];
      acc[0]=f32x4{0,0,0,0}; acc[1]=f32x4{0,0,0,0};
      for (int kk=0; kk<8; ++kk){
        const int k0 = kk*32 + kof;
        const int row = wave*16 + lr;
        u32x4 raw = u32x4{0u,0u,0u,0u};
        if (row < MROWS) raw = *(const u32x4*)&s_ns[row][SWZ(row,k0)];
        const bf16x8 afr = __builtin_bit_cast(bf16x8, raw);
        #pragma unroll
        for (int nt=0;nt<2;++nt){
          const bf16x8 bfr = __builtin_bit_cast(bf16x8, *(const u32x4*)(P.W1b + (size_t)(nt*16+lr)*256 + k0));
          acc[nt] = mfma16(afr, bfr, acc[nt]);
        }
      }
      #pragma unroll
      for (int nt=0;nt<2;++nt){
        const int c = nt*16 + lr;
        const float bias = P.b1[c];
        #pragma unroll
        for (int q=0;q<4;++q){
          const int row = wave*16 + dr + q;
          if (row < MROWS) s_h1[row][c] = f2bf(silu_f(acc[nt][q] + bias));
        }
      }
      { // P8
        const int row_a = wave*16 + lr;
        u32x4 raw = u32x4{0u,0u,0u,0u};
        if (row_a < MROWS) raw = *(const u32x4*)&s_h1[row_a][kof];
        const bf16x8 a = __builtin_bit_cast(bf16x8, raw);
        const bf16x8 b = __builtin_bit_cast(bf16x8, *(const u32x4*)(P.W2b + (size_t)lr*32 + kof));
        f32x4 acc2 = mfma16(a, b, f32x4{0,0,0,0});
        const float bias = P.b2[lr];
        #pragma unroll
        for (int q=0;q<4;++q){
          const int row = wave*16 + dr + q;
          if (row < MROWS){
            s_h1[row][lr]    = f2bf(silu_f(acc2[q] + bias));
            s_h1[row][lr+16] = 0;
          }
        }
      }
    }
    __syncthreads();

    // ---- P9: sig += silu(h2 @ W3p^T + b3)   (K=32 padded from 16)
    {
      bf16x8 afr[MT];
      #pragma unroll
      for (int mt=0;mt<MT;++mt){
        const int row = mt*16 + lr;
        u32x4 raw = u32x4{0u,0u,0u,0u};
        if (row < MROWS) raw = *(const u32x4*)&s_h1[row][kof];
        afr[mt] = __builtin_bit_cast(bf16x8, raw);
      }
      #pragma unroll
      for (int nt=0;nt<4;++nt){
        const int n = (wave*4+nt)*16 + lr;
        const bf16x8 bfr = __builtin_bit_cast(bf16x8, *(const u32x4*)(P.W3p + (size_t)n*32 + kof));
        const float b3v = P.b3[n];
        #pragma unroll
        for (int mt=0;mt<MT;++mt){
          const f32x4 acc = mfma16(afr[mt], bfr, f32x4{0,0,0,0});
          #pragma unroll
          for (int q=0;q<4;++q){
            const int row = mt*16 + dr + q;
            if (row < MROWS){
              const int si = SWZ(row,n);
              s_sig[row][si] = f2bf(bf2f(s_sig[row][si]) + silu_f(acc[q] + b3v));
            }
          }
        }
      }
    }
    __syncthreads();
  } // layers

  // ---- final LN -> out (f32)
  {
    for (int r = wave; r < MROWS; r += 4){
      const int col = lane*4;
      const u32x2 raw = *(const u32x2*)&s_sig[r][SWZ(r,col)];
      const float x0 = bfloat_lo(raw[0]), x1 = bfloat_hi(raw[0]);
      const float x2 = bfloat_lo(raw[1]), x3 = bfloat_hi(raw[1]);
      const float m = wred(x0+x1+x2+x3)*(1.f/256.f);
      const float d0=x0-m, d1=x1-m, d2=x2-m, d3=x3-m;
      const float rs = rsqrtf(wred(d0*d0+d1*d1+d2*d2+d3*d3)*(1.f/256.f)+1e-10f);
      const float4 gv = *(const float4*)(P.g_fin+col);
      const float4 bv = *(const float4*)(P.b_fin+col);
      float4 o;
      o.x = d0*rs*gv.x+bv.x; o.y = d1*rs*gv.y+bv.y;
      o.z = d2*rs*gv.z+bv.z; o.w = d3*rs*gv.w+bv.w;
      *(float4*)(P.out + ((size_t)b0*MROWS + r)*256 + col) = o;
    }
  }
}

extern "C" void kernel_launch(void* const* d_in, const int* in_sizes, int n_in,
                              void* d_out, int out_size, void* d_ws, size_t ws_size,
                              hipStream_t stream) {
  (void)in_sizes; (void)n_in; (void)out_size; (void)ws_size;
  const float* sigIn   = (const float*)d_in[0];
  const float* ctx     = (const float*)d_in[1];
  const float* Ws      = (const float*)d_in[2];
  const float* bs      = (const float*)d_in[3];
  const float* bn_g    = (const float*)d_in[4];
  const float* bn_b    = (const float*)d_in[5];
  const float* cWq     = (const float*)d_in[6];
  const float* cWk     = (const float*)d_in[7];
  const float* cWv     = (const float*)d_in[8];
  const float* cbq     = (const float*)d_in[9];
  const float* cbk     = (const float*)d_in[10];
  const float* cbv     = (const float*)d_in[11];
  const float* cbias_k = (const float*)d_in[12];
  const float* cbias_v = (const float*)d_in[13];
  const float* cWo     = (const float*)d_in[14];
  const float* cbo     = (const float*)d_in[15];
  const float* xWq     = (const float*)d_in[16];
  const float* xWk     = (const float*)d_in[17];
  const float* xWv     = (const float*)d_in[18];
  const float* xbq     = (const float*)d_in[19];
  const float* xbk     = (const float*)d_in[20];
  const float* xbv     = (const float*)d_in[21];
  const float* xbias_k = (const float*)d_in[22];
  const float* xbias_v = (const float*)d_in[23];
  const float* xWo     = (const float*)d_in[24];
  const float* xbo     = (const float*)d_in[25];
  const float* W1      = (const float*)d_in[26];
  const float* b1      = (const float*)d_in[27];
  const float* W2      = (const float*)d_in[28];
  const float* b2      = (const float*)d_in[29];
  const float* W3      = (const float*)d_in[30];
  const float* b3      = (const float*)d_in[31];
  const float* g_ff    = (const float*)d_in[32];
  const float* b_ff    = (const float*)d_in[33];
  const float* g_cas   = (const float*)d_in[34];
  const float* b_cas   = (const float*)d_in[35];
  const float* g_fin   = (const float*)d_in[36];
  const float* b_fin   = (const float*)d_in[37];

  char* ws = (char*)d_ws;
  u16*  Wv    = (u16*)(ws);             // 131072 B
  u16*  Wo    = (u16*)(ws + 131072);    // 131072 B
  u16*  Wq3   = (u16*)(ws + 262144);    // 16384 B
  u16*  W1b   = (u16*)(ws + 278528);    // 16384 B
  u16*  W2b   = (u16*)(ws + 294912);    // 1024 B
  u16*  W3p   = (u16*)(ws + 295936);    // 16384 B
  float* bias3= (float*)(ws + 312320);  // 96 B (pad to 128)
  float* ecr_t= (float*)(ws + 312448);  // 294912 B (transposed [18][4096])
  float* mu   = (float*)(ws + 607360);  // 72 B (pad)
  float* rstd = (float*)(ws + 607488);  // 72 B

  k_prep<<<dim3(64), dim3(256), 0, stream>>>(xWq, xWk, xWv, xWo, xbq, xbk, xbias_k,
                                             W1, W2, W3, Wv, Wo, Wq3, W1b, W2b, W3p, bias3);
  k_ec<<<dim3(1024), dim3(256), 0, stream>>>(ctx, Ws, bs, ecr_t);
  k_bn<<<dim3(18), dim3(256), 0, stream>>>(ecr_t, mu, rstd);

  Params P;
  P.sigIn = sigIn; P.bn_g = bn_g; P.bn_b = bn_b;
  P.cWq=cWq; P.cWk=cWk; P.cWv=cWv; P.cbq=cbq; P.cbk=cbk; P.cbv=cbv;
  P.cbias_k=cbias_k; P.cbias_v=cbias_v; P.cWo=cWo; P.cbo=cbo;
  P.xbv=xbv; P.xbias_v=xbias_v; P.xbo=xbo;
  P.b1=b1; P.b2=b2; P.b3=b3;
  P.g_cas=g_cas; P.b_cas=b_cas; P.g_ff=g_ff; P.b_ff=b_ff; P.g_fin=g_fin; P.b_fin=b_fin;
  P.Wv=Wv; P.Wo=Wo; P.Wq3=Wq3; P.W1b=W1b; P.W2b=W2b; P.W3p=W3p;
  P.bias3=bias3; P.ecr_t=ecr_t; P.mu=mu; P.rstd=rstd;
  P.out = (float*)d_out;

  k_main<<<dim3(2048), dim3(256), 0, stream>>>(P);
}